// Round 4
// baseline (880.011 us; speedup 1.0000x reference)
//
#include <hip/hip_runtime.h>

#define N_NODES   100000
#define BIN_NODES 1024
#define NBIN_D    98                  // ceil(100000/1024) dst bins
#define NSUB      7                   // src octants: src>>14 in 0..6
#define NBINS_TOT (NBIN_D * NSUB)     // 686 sort bins
#define NCHUNK    512
#define PS16      17                  // padded LDS stride for F=16
#define NSPLIT    7

// ---------------- bf16 helpers ----------------
__device__ __forceinline__ float blo(unsigned u) { return __uint_as_float(u << 16); }
__device__ __forceinline__ float bhi(unsigned u) { return __uint_as_float(u & 0xFFFF0000u); }
__device__ __forceinline__ unsigned bpack(float a, float b) {
    unsigned ua = __float_as_uint(a), ub = __float_as_uint(b);
    unsigned ra = (ua + 0x7FFFu + ((ua >> 16) & 1u)) >> 16;
    unsigned rb = (ub + 0x7FFFu + ((ub >> 16) & 1u)) >> 16;
    return ra | (rb << 16);
}

// ---------------- dtype detection ----------------
__global__ void detect_i64_kernel(const unsigned int* __restrict__ e,
                                  unsigned int* __restrict__ flag) {
    int i = blockIdx.x * blockDim.x + threadIdx.x;  // 0..2047
    unsigned int v = e[2 * i + 1];
    if (v != 0u) atomicOr(flag, 1u);
}

// ---------------- pack x (N x 5 f32) -> bf16x8 in uint4 ----------------
__global__ void pack_x_kernel(const float* __restrict__ x, uint4* __restrict__ xpad, int N) {
    int n = blockIdx.x * blockDim.x + threadIdx.x;
    if (n >= N) return;
    const float* p = x + (long long)n * 5;
    uint4 v;
    v.x = bpack(p[0], p[1]);
    v.y = bpack(p[2], p[3]);
    v.z = bpack(p[4], 0.f);
    v.w = 0u;
    xpad[n] = v;
}

// ---------------- pass 1: per-chunk histogram over sort bins ----------------
__global__ void count_kernel(const void* __restrict__ eidx,
                             const unsigned int* __restrict__ flag,
                             int* __restrict__ hist, int E) {
    __shared__ int lh[NBINS_TOT];
    int tid = threadIdx.x, c = blockIdx.x;
    for (int i = tid; i < NBINS_TOT; i += blockDim.x) lh[i] = 0;
    __syncthreads();
    int per = (E + NCHUNK - 1) / NCHUNK;
    int e0 = c * per, e1 = min(E, e0 + per);
    unsigned int is32 = *flag;
    for (int e = e0 + tid; e < e1; e += blockDim.x) {
        int s, d;
        if (is32) {
            const int* p = (const int*)eidx; s = p[e]; d = p[E + e];
        } else {
            const long long* p = (const long long*)eidx; s = (int)p[e]; d = (int)p[E + e];
        }
        atomicAdd(&lh[(d >> 10) * NSUB + (s >> 14)], 1);
    }
    __syncthreads();
    for (int i = tid; i < NBINS_TOT; i += blockDim.x) hist[c * NBINS_TOT + i] = lh[i];
}

// ---------------- pass 2a: per-bin column scan (1 wave per bin) -------------
__global__ void scan1_kernel(const int* __restrict__ hist,
                             int* __restrict__ off_rel,
                             int* __restrict__ totals) {
    int gtid = blockIdx.x * blockDim.x + threadIdx.x;
    int b = gtid >> 6;
    int lane = threadIdx.x & 63;
    if (b >= NBINS_TOT) return;
    int carry = 0;
    for (int k = 0; k < NCHUNK; k += 64) {
        int v = hist[(k + lane) * NBINS_TOT + b];
        int sc = v;
        for (int off = 1; off < 64; off <<= 1) {
            int t = __shfl_up(sc, off);
            if (lane >= off) sc += t;
        }
        off_rel[(k + lane) * NBINS_TOT + b] = carry + sc - v;   // exclusive
        carry += __shfl(sc, 63);
    }
    if (lane == 0) totals[b] = carry;
}

// ---------------- pass 2b: scan bin totals -> bin_start ---------------------
__global__ void scan2_kernel(const int* __restrict__ totals,
                             int* __restrict__ bin_start) {
    __shared__ int buf[1024];
    int tid = threadIdx.x;
    buf[tid] = (tid < NBINS_TOT) ? totals[tid] : 0;
    __syncthreads();
    for (int off = 1; off < 1024; off <<= 1) {
        int v = (tid >= off) ? buf[tid - off] : 0;
        __syncthreads();
        buf[tid] += v;
        __syncthreads();
    }
    if (tid < NBINS_TOT) bin_start[tid + 1] = buf[tid];
    if (tid == 0) bin_start[0] = 0;
}

// ---------------- pass 3: scatter edges into bin-sorted order ---------------
// packed edge: (dst_local << 17) | src
__global__ void scatter_kernel(const void* __restrict__ eidx,
                               const unsigned int* __restrict__ flag,
                               const int* __restrict__ off_rel,
                               const int* __restrict__ bin_start,
                               unsigned int* __restrict__ sorted, int E) {
    __shared__ int lcnt[NBINS_TOT];
    __shared__ int lbase[NBINS_TOT];
    int tid = threadIdx.x, c = blockIdx.x;
    for (int i = tid; i < NBINS_TOT; i += blockDim.x) {
        lcnt[i] = 0;
        lbase[i] = bin_start[i] + off_rel[c * NBINS_TOT + i];
    }
    __syncthreads();
    int per = (E + NCHUNK - 1) / NCHUNK;
    int e0 = c * per, e1 = min(E, e0 + per);
    unsigned int is32 = *flag;
    for (int e = e0 + tid; e < e1; e += blockDim.x) {
        int s, d;
        if (is32) {
            const int* p = (const int*)eidx; s = p[e]; d = p[E + e];
        } else {
            const long long* p = (const long long*)eidx; s = (int)p[e]; d = (int)p[E + e];
        }
        int b = (d >> 10) * NSUB + (s >> 14);
        int dl = d & 1023;
        int pos = lbase[b] + atomicAdd(&lcnt[b], 1);
        sorted[pos] = ((unsigned int)dl << 17) | (unsigned int)s;
    }
}

// ---------------- aggregation, F=16 (layer 2), bf16 h -----------------------
// 2 lanes/edge, uint4 (8 bf16) per lane -> 32 edges in flight per wave
__global__ __launch_bounds__(1024) void agg16_kernel(
    const unsigned int* __restrict__ sorted, const int* __restrict__ bin_start,
    const uint4* __restrict__ hb, unsigned int* __restrict__ partial, int S, int N) {
    __shared__ float lagg[BIN_NODES * PS16];   // 69,632 B -> 2 blocks/CU
    int tid = threadIdx.x, s = blockIdx.x, bin = blockIdx.y;
    for (int i = tid; i < BIN_NODES * PS16; i += 1024) lagg[i] = 0.f;
    __syncthreads();
    int bs = bin_start[bin * NSUB], be = bin_start[(bin + 1) * NSUB];
    int cnt = be - bs, per = (cnt + S - 1) / S;
    int e0 = bs + s * per, e1 = min(be, e0 + per);
    int g = tid >> 1, q = tid & 1;            // 512 groups x 2 lanes
#pragma unroll 4
    for (int e = e0 + g; e < e1; e += 512) {
        unsigned int p = sorted[e];
        int src = (int)(p & 0x1FFFF), dl = (int)(p >> 17);
        uint4 v = hb[src * 2 + q];
        float* d = &lagg[dl * PS16 + q * 8];
        atomicAdd(&d[0], blo(v.x)); atomicAdd(&d[1], bhi(v.x));
        atomicAdd(&d[2], blo(v.y)); atomicAdd(&d[3], bhi(v.y));
        atomicAdd(&d[4], blo(v.z)); atomicAdd(&d[5], bhi(v.z));
        atomicAdd(&d[6], blo(v.w)); atomicAdd(&d[7], bhi(v.w));
    }
    __syncthreads();
    int base = bin * BIN_NODES;
    int bn = min(BIN_NODES, N - base);
    unsigned int* out = partial + ((size_t)s * N + base) * 8;
    for (int i = tid; i < bn * 8; i += 1024) {
        int node = i >> 3, j = i & 7;
        out[node * 8 + j] = bpack(lagg[node * PS16 + j * 2], lagg[node * PS16 + j * 2 + 1]);
    }
}

// ---------------- aggregation, F=5 (layer 1), bf16 xpad ---------------------
__global__ __launch_bounds__(1024) void agg5_kernel(
    const unsigned int* __restrict__ sorted, const int* __restrict__ bin_start,
    const uint4* __restrict__ xpad, float* __restrict__ partial, int S, int N) {
    __shared__ float lagg[BIN_NODES * 5];     // 20,480 B
    int tid = threadIdx.x, s = blockIdx.x, bin = blockIdx.y;
    for (int i = tid; i < BIN_NODES * 5; i += 1024) lagg[i] = 0.f;
    __syncthreads();
    int bs = bin_start[bin * NSUB], be = bin_start[(bin + 1) * NSUB];
    int cnt = be - bs, per = (cnt + S - 1) / S;
    int e0 = bs + s * per, e1 = min(be, e0 + per);
#pragma unroll 4
    for (int e = e0 + tid; e < e1; e += 1024) {
        unsigned int p = sorted[e];
        int src = (int)(p & 0x1FFFF), dl = (int)(p >> 17);
        uint4 v = xpad[src];
        float* d = &lagg[dl * 5];
        atomicAdd(&d[0], blo(v.x)); atomicAdd(&d[1], bhi(v.x));
        atomicAdd(&d[2], blo(v.y)); atomicAdd(&d[3], bhi(v.y));
        atomicAdd(&d[4], blo(v.z));
    }
    __syncthreads();
    int base = bin * BIN_NODES;
    int bn = min(BIN_NODES, N - base);
    float* out = partial + (size_t)s * N * 5;
    for (int i = tid; i < bn * 5; i += 1024) out[(size_t)base * 5 + i] = lagg[i];
}

// ------------- MLP1: hb = bf16( relu((x+sum p1)@W1a+b1a)@W1b+b1b ) ----------
__global__ void mlp1b_kernel(const float* __restrict__ x,
                             const float* __restrict__ partial, int S,
                             const float* __restrict__ W1, const float* __restrict__ b1,
                             const float* __restrict__ W2, const float* __restrict__ b2,
                             uint4* __restrict__ hb, int N) {
    int n = blockIdx.x * blockDim.x + threadIdx.x;
    if (n >= N) return;
    float in[5];
#pragma unroll
    for (int f = 0; f < 5; ++f) in[f] = x[(long long)n * 5 + f];
    for (int s = 0; s < S; ++s) {
        const float* p = partial + (size_t)s * N * 5 + (long long)n * 5;
#pragma unroll
        for (int f = 0; f < 5; ++f) in[f] += p[f];
    }
    float hid[16];
#pragma unroll
    for (int j = 0; j < 16; ++j) {
        float acc = b1[j];
#pragma unroll
        for (int f = 0; f < 5; ++f) acc = fmaf(in[f], W1[f * 16 + j], acc);
        hid[j] = fmaxf(acc, 0.0f);
    }
    float o[16];
#pragma unroll
    for (int j = 0; j < 16; ++j) {
        float acc = b2[j];
#pragma unroll
        for (int k = 0; k < 16; ++k) acc = fmaf(hid[k], W2[k * 16 + j], acc);
        o[j] = acc;
    }
    uint4 a, b;
    a.x = bpack(o[0], o[1]);  a.y = bpack(o[2], o[3]);
    a.z = bpack(o[4], o[5]);  a.w = bpack(o[6], o[7]);
    b.x = bpack(o[8], o[9]);  b.y = bpack(o[10], o[11]);
    b.z = bpack(o[12], o[13]); b.w = bpack(o[14], o[15]);
    hb[n * 2] = a;
    hb[n * 2 + 1] = b;
}

// ------------- MLP2: out = relu((h+sum p2)@W2a+b2a)@W2b+b2b -----------------
__global__ void mlp2b_kernel(const uint4* __restrict__ hb,
                             const uint4* __restrict__ p2, int S,
                             const float* __restrict__ W1, const float* __restrict__ b1,
                             const float* __restrict__ W2, const float* __restrict__ b2,
                             float* __restrict__ out, int N) {
    int n = blockIdx.x * blockDim.x + threadIdx.x;
    if (n >= N) return;
    float in[16];
    {
        uint4 a = hb[n * 2], b = hb[n * 2 + 1];
        in[0] = blo(a.x); in[1] = bhi(a.x); in[2] = blo(a.y); in[3] = bhi(a.y);
        in[4] = blo(a.z); in[5] = bhi(a.z); in[6] = blo(a.w); in[7] = bhi(a.w);
        in[8] = blo(b.x); in[9] = bhi(b.x); in[10] = blo(b.y); in[11] = bhi(b.y);
        in[12] = blo(b.z); in[13] = bhi(b.z); in[14] = blo(b.w); in[15] = bhi(b.w);
    }
    for (int s = 0; s < S; ++s) {
        uint4 a = p2[((size_t)s * N + n) * 2], b = p2[((size_t)s * N + n) * 2 + 1];
        in[0] += blo(a.x); in[1] += bhi(a.x); in[2] += blo(a.y); in[3] += bhi(a.y);
        in[4] += blo(a.z); in[5] += bhi(a.z); in[6] += blo(a.w); in[7] += bhi(a.w);
        in[8] += blo(b.x); in[9] += bhi(b.x); in[10] += blo(b.y); in[11] += bhi(b.y);
        in[12] += blo(b.z); in[13] += bhi(b.z); in[14] += blo(b.w); in[15] += bhi(b.w);
    }
    float hid[16];
#pragma unroll
    for (int j = 0; j < 16; ++j) {
        float acc = b1[j];
#pragma unroll
        for (int f = 0; f < 16; ++f) acc = fmaf(in[f], W1[f * 16 + j], acc);
        hid[j] = fmaxf(acc, 0.0f);
    }
#pragma unroll
    for (int j = 0; j < 16; ++j) {
        float acc = b2[j];
#pragma unroll
        for (int k = 0; k < 16; ++k) acc = fmaf(hid[k], W2[k * 16 + j], acc);
        out[(long long)n * 16 + j] = acc;
    }
}

// ---------- fallback path (ws too small): global atomics, fp32 --------------
__device__ __forceinline__ void load_edge(const void* eidx, unsigned int is32,
                                          int i, int E, int& s, int& d) {
    if (is32 == 0u) {
        const long long* p = (const long long*)eidx;
        s = (int)p[i]; d = (int)p[E + i];
    } else {
        const int* p = (const int*)eidx;
        s = p[i]; d = p[E + i];
    }
}

__global__ void scatter_f5_kernel(const void* __restrict__ eidx,
                                  const unsigned int* __restrict__ flag,
                                  const float* __restrict__ x,
                                  float* __restrict__ agg, int E) {
    int i = blockIdx.x * blockDim.x + threadIdx.x;
    if (i >= E) return;
    int s, d; load_edge(eidx, *flag, i, E, s, d);
    const float* xs = x + (long long)s * 5;
    float* a = agg + (long long)d * 5;
#pragma unroll
    for (int f = 0; f < 5; ++f) atomicAdd(&a[f], xs[f]);
}

__global__ void scatter_f16_kernel(const void* __restrict__ eidx,
                                   const unsigned int* __restrict__ flag,
                                   const float* __restrict__ h,
                                   float* __restrict__ agg, int E) {
    int i = blockIdx.x * blockDim.x + threadIdx.x;
    if (i >= E) return;
    int s, d; load_edge(eidx, *flag, i, E, s, d);
    const float* hs = h + (long long)s * 16;
    float* a = agg + (long long)d * 16;
#pragma unroll
    for (int f = 0; f < 16; ++f) atomicAdd(&a[f], hs[f]);
}

__global__ void mlp1_kernel(const float* __restrict__ x,
                            const float* __restrict__ agg,
                            const float* __restrict__ W1, const float* __restrict__ b1,
                            const float* __restrict__ W2, const float* __restrict__ b2,
                            float* __restrict__ out, int N) {
    int n = blockIdx.x * blockDim.x + threadIdx.x;
    if (n >= N) return;
    float in[5];
#pragma unroll
    for (int f = 0; f < 5; ++f)
        in[f] = x[(long long)n * 5 + f] + agg[(long long)n * 5 + f];
    float hid[16];
#pragma unroll
    for (int j = 0; j < 16; ++j) {
        float acc = b1[j];
#pragma unroll
        for (int f = 0; f < 5; ++f) acc = fmaf(in[f], W1[f * 16 + j], acc);
        hid[j] = fmaxf(acc, 0.0f);
    }
#pragma unroll
    for (int j = 0; j < 16; ++j) {
        float acc = b2[j];
#pragma unroll
        for (int k = 0; k < 16; ++k) acc = fmaf(hid[k], W2[k * 16 + j], acc);
        out[(long long)n * 16 + j] = acc;
    }
}

__global__ void mlp2_kernel(const float* __restrict__ h,
                            const float* __restrict__ agg,
                            const float* __restrict__ W1, const float* __restrict__ b1,
                            const float* __restrict__ W2, const float* __restrict__ b2,
                            float* __restrict__ out, int N) {
    int n = blockIdx.x * blockDim.x + threadIdx.x;
    if (n >= N) return;
    float in[16];
#pragma unroll
    for (int f = 0; f < 16; ++f)
        in[f] = h[(long long)n * 16 + f] + agg[(long long)n * 16 + f];
    float hid[16];
#pragma unroll
    for (int j = 0; j < 16; ++j) {
        float acc = b1[j];
#pragma unroll
        for (int f = 0; f < 16; ++f) acc = fmaf(in[f], W1[f * 16 + j], acc);
        hid[j] = fmaxf(acc, 0.0f);
    }
#pragma unroll
    for (int j = 0; j < 16; ++j) {
        float acc = b2[j];
#pragma unroll
        for (int k = 0; k < 16; ++k) acc = fmaf(hid[k], W2[k * 16 + j], acc);
        out[(long long)n * 16 + j] = acc;
    }
}

extern "C" void kernel_launch(void* const* d_in, const int* in_sizes, int n_in,
                              void* d_out, int out_size, void* d_ws, size_t ws_size,
                              hipStream_t stream) {
    const float* x    = (const float*)d_in[0];
    const void*  eidx = d_in[1];
    const float* W1a  = (const float*)d_in[2];
    const float* b1a  = (const float*)d_in[3];
    const float* W1b  = (const float*)d_in[4];
    const float* b1b  = (const float*)d_in[5];
    const float* W2a  = (const float*)d_in[6];
    const float* b2a  = (const float*)d_in[7];
    const float* W2b  = (const float*)d_in[8];
    const float* b2b  = (const float*)d_in[9];
    float* out = (float*)d_out;

    const int E = in_sizes[1] / 2;
    const int N = N_NODES;

    char* ws = (char*)d_ws;
    auto align256 = [](size_t v) { return (v + 255) & ~(size_t)255; };
    const size_t hist_bytes = (size_t)NCHUNK * NBINS_TOT * 4;          // 1.40 MB

    const size_t off_flag     = 0;
    const size_t off_binstart = 256;                                   // 687*4
    const size_t off_totals   = align256(off_binstart + (NBINS_TOT + 1) * 4);
    const size_t off_hist     = align256(off_totals + NBINS_TOT * 4);
    const size_t off_offrel   = align256(off_hist + hist_bytes);
    const size_t off_sorted   = align256(off_offrel + hist_bytes);
    const size_t off_xpad     = align256(off_sorted + (size_t)E * 4);
    const size_t off_hb       = align256(off_xpad + (size_t)N * 16);   // bf16x8
    const size_t off_p1       = align256(off_hb + (size_t)N * 32);     // bf16x16
    const size_t per_S_bytes  = (size_t)N * 5 * 4 + (size_t)N * 16 * 2; // 5.2 MB

    unsigned int* flag = (unsigned int*)(ws + off_flag);
    int S = 0;
    if (ws_size > off_p1) S = (int)((ws_size - off_p1) / per_S_bytes);
    if (S > NSPLIT) S = NSPLIT;

    if (S >= 1) {
        int* bin_start       = (int*)(ws + off_binstart);
        int* totals          = (int*)(ws + off_totals);
        int* hist            = (int*)(ws + off_hist);
        int* off_rel         = (int*)(ws + off_offrel);
        unsigned int* sorted = (unsigned int*)(ws + off_sorted);
        uint4* xpad          = (uint4*)(ws + off_xpad);
        uint4* hb            = (uint4*)(ws + off_hb);
        float* p1            = (float*)(ws + off_p1);
        uint4* p2            = (uint4*)(ws + off_p1 + (size_t)S * N * 5 * 4);

        hipMemsetAsync(ws, 0, 4, stream);
        detect_i64_kernel<<<8, 256, 0, stream>>>((const unsigned int*)eidx, flag);
        pack_x_kernel<<<(N + 255) / 256, 256, 0, stream>>>(x, xpad, N);
        count_kernel<<<NCHUNK, 256, 0, stream>>>(eidx, flag, hist, E);
        scan1_kernel<<<(NBINS_TOT * 64 + 511) / 512, 512, 0, stream>>>(hist, off_rel, totals);
        scan2_kernel<<<1, 1024, 0, stream>>>(totals, bin_start);
        scatter_kernel<<<NCHUNK, 256, 0, stream>>>(eidx, flag, off_rel, bin_start, sorted, E);

        dim3 agrid(S, NBIN_D);
        agg5_kernel<<<agrid, 1024, 0, stream>>>(sorted, bin_start, xpad, p1, S, N);
        mlp1b_kernel<<<(N + 255) / 256, 256, 0, stream>>>(x, p1, S, W1a, b1a, W1b, b1b, hb, N);
        agg16_kernel<<<agrid, 1024, 0, stream>>>(sorted, bin_start, hb, (unsigned int*)p2, S, N);
        mlp2b_kernel<<<(N + 255) / 256, 256, 0, stream>>>(hb, p2, S, W2a, b2a, W2b, b2b, out, N);
    } else {
        // fallback: global-atomic path
        const size_t f_agg1 = 4096;
        const size_t f_agg2 = f_agg1 + 2 * 1024 * 1024;
        const size_t f_h    = f_agg2 + 7 * 1024 * 1024;
        float* agg1 = (float*)(ws + f_agg1);
        float* agg2 = (float*)(ws + f_agg2);
        float* h    = (float*)(ws + f_h);

        hipMemsetAsync(ws, 0, f_agg2 + (size_t)N * 16 * 4, stream);
        detect_i64_kernel<<<8, 256, 0, stream>>>((const unsigned int*)eidx, flag);
        int blocks = (E + 255) / 256;
        scatter_f5_kernel<<<blocks, 256, 0, stream>>>(eidx, flag, x, agg1, E);
        mlp1_kernel<<<(N + 255) / 256, 256, 0, stream>>>(x, agg1, W1a, b1a, W1b, b1b, h, N);
        scatter_f16_kernel<<<blocks, 256, 0, stream>>>(eidx, flag, h, agg2, E);
        mlp2_kernel<<<(N + 255) / 256, 256, 0, stream>>>(h, agg2, W2a, b2a, W2b, b2b, out, N);
    }
}

// Round 6
// 373.706 us; speedup vs baseline: 2.3548x; 2.3548x over previous
//
#include <hip/hip_runtime.h>

#define N_NODES 100000
#define NBIN_D  98            // pass-1 dst bins of 1024 nodes
#define NCHUNK  512

// ---------------- dtype detection (int64 vs int32 edge_index) ---------------
// edge values < 2^31. If int64 LE, every odd 32-bit word is 0.
__global__ void detect_i64_kernel(const unsigned int* __restrict__ e,
                                  unsigned int* __restrict__ flag) {
    int i = blockIdx.x * blockDim.x + threadIdx.x;  // 0..2047
    unsigned int v = e[2 * i + 1];
    if (v != 0u) atomicOr(flag, 1u);
}

// ---------------- pad x (N x 5 f32) -> fp32x8 (32B rows) --------------------
__global__ void pad_x_kernel(const float* __restrict__ x, float4* __restrict__ xp, int N) {
    int n = blockIdx.x * blockDim.x + threadIdx.x;
    if (n >= N) return;
    const float* p = x + (long long)n * 5;
    xp[n * 2]     = make_float4(p[0], p[1], p[2], p[3]);
    xp[n * 2 + 1] = make_float4(p[4], 0.f, 0.f, 0.f);
}

// ---------------- pass 1a: per-chunk histogram over 98 dst bins -------------
__global__ void count_kernel(const void* __restrict__ eidx,
                             const unsigned int* __restrict__ flag,
                             int* __restrict__ hist, int E) {
    __shared__ int lh[NBIN_D];
    int tid = threadIdx.x, c = blockIdx.x;
    for (int i = tid; i < NBIN_D; i += blockDim.x) lh[i] = 0;
    __syncthreads();
    int per = (E + NCHUNK - 1) / NCHUNK;
    int e0 = c * per, e1 = min(E, e0 + per);
    unsigned int is32 = *flag;
    for (int e = e0 + tid; e < e1; e += blockDim.x) {
        int d = is32 ? ((const int*)eidx)[E + e]
                     : (int)((const long long*)eidx)[E + e];
        atomicAdd(&lh[d >> 10], 1);
    }
    __syncthreads();
    for (int i = tid; i < NBIN_D; i += blockDim.x) hist[c * NBIN_D + i] = lh[i];
}

// ---------------- pass 1b: per-bin column scan (1 wave per bin) -------------
__global__ void scan1_kernel(const int* __restrict__ hist,
                             int* __restrict__ off_rel,
                             int* __restrict__ totals) {
    int gtid = blockIdx.x * blockDim.x + threadIdx.x;
    int b = gtid >> 6;
    int lane = threadIdx.x & 63;
    if (b >= NBIN_D) return;
    int carry = 0;
    for (int k = 0; k < NCHUNK; k += 64) {
        int v = hist[(k + lane) * NBIN_D + b];
        int sc = v;
        for (int off = 1; off < 64; off <<= 1) {
            int t = __shfl_up(sc, off);
            if (lane >= off) sc += t;
        }
        off_rel[(k + lane) * NBIN_D + b] = carry + sc - v;   // exclusive
        carry += __shfl(sc, 63);
    }
    if (lane == 0) totals[b] = carry;
}

// ---------------- pass 1c: scan bin totals -> bin_start ---------------------
__global__ void scan2_kernel(const int* __restrict__ totals,
                             int* __restrict__ bin_start) {
    __shared__ int buf[1024];
    int tid = threadIdx.x;
    buf[tid] = (tid < NBIN_D) ? totals[tid] : 0;
    __syncthreads();
    for (int off = 1; off < 1024; off <<= 1) {
        int v = (tid >= off) ? buf[tid - off] : 0;
        __syncthreads();
        buf[tid] += v;
        __syncthreads();
    }
    if (tid < NBIN_D) bin_start[tid + 1] = buf[tid];
    if (tid == 0) bin_start[0] = 0;
}

// ---------------- pass 1d: scatter edges into dst-bin order -----------------
// packed edge word: (dl << 17) | src   (dl = dst & 1023, src < 2^17)
__global__ void scatter1_kernel(const void* __restrict__ eidx,
                                const unsigned int* __restrict__ flag,
                                const int* __restrict__ off_rel,
                                const int* __restrict__ bin_start,
                                unsigned int* __restrict__ sorted1, int E) {
    __shared__ int lcnt[NBIN_D];
    __shared__ int lbase[NBIN_D];
    int tid = threadIdx.x, c = blockIdx.x;
    for (int i = tid; i < NBIN_D; i += blockDim.x) {
        lcnt[i] = 0;
        lbase[i] = bin_start[i] + off_rel[c * NBIN_D + i];
    }
    __syncthreads();
    int per = (E + NCHUNK - 1) / NCHUNK;
    int e0 = c * per, e1 = min(E, e0 + per);
    unsigned int is32 = *flag;
    for (int e = e0 + tid; e < e1; e += blockDim.x) {
        int s, d;
        if (is32) {
            const int* p = (const int*)eidx; s = p[e]; d = p[E + e];
        } else {
            const long long* p = (const long long*)eidx; s = (int)p[e]; d = (int)p[E + e];
        }
        int b = d >> 10;
        int dl = d & 1023;
        int pos = lbase[b] + atomicAdd(&lcnt[b], 1);
        sorted1[pos] = ((unsigned int)dl << 17) | (unsigned int)s;
    }
}

// ---------------- pass 2: per-bin counting sort by dl -> CSR ----------------
__global__ __launch_bounds__(1024) void dlsort_kernel(
    const unsigned int* __restrict__ sorted1,
    const int* __restrict__ bin_start,
    unsigned int* __restrict__ sorted2,
    int* __restrict__ row_ptr, int N) {
    __shared__ int hist[1024];
    __shared__ int scanv[1024];
    __shared__ int offc[1024];
    int tid = threadIdx.x, b = blockIdx.x;
    int bs = bin_start[b], be = bin_start[b + 1];
    hist[tid] = 0;
    __syncthreads();
    for (int e = bs + tid; e < be; e += 1024)
        atomicAdd(&hist[sorted1[e] >> 17], 1);
    __syncthreads();
    scanv[tid] = hist[tid];
    __syncthreads();
    for (int off = 1; off < 1024; off <<= 1) {
        int v = (tid >= off) ? scanv[tid - off] : 0;
        __syncthreads();
        scanv[tid] += v;
        __syncthreads();
    }
    int excl = scanv[tid] - hist[tid];
    offc[tid] = excl;
    int node = b * 1024 + tid;
    if (node < N) row_ptr[node] = bs + excl;
    if (node == N) row_ptr[N] = be;   // N=100000 -> b=97, tid=672
    __syncthreads();
    for (int e = bs + tid; e < be; e += 1024) {
        unsigned int w = sorted1[e];
        int pos = bs + atomicAdd(&offc[w >> 17], 1);
        sorted2[pos] = w;
    }
}

// ---------------- aggregation F=5 (layer 1): CSR, zero atomics --------------
__global__ __launch_bounds__(256) void agg5_csr(
    const unsigned int* __restrict__ sorted2, const int* __restrict__ row_ptr,
    const float4* __restrict__ xp, float* __restrict__ agg, int N) {
    int n = blockIdx.x * 256 + threadIdx.x;
    if (n >= N) return;
    int e0 = row_ptr[n], e1 = row_ptr[n + 1];
    float a0 = 0, a1 = 0, a2 = 0, a3 = 0, a4 = 0;
    int e = e0;
    for (; e + 1 < e1; e += 2) {
        int s0 = (int)(sorted2[e] & 0x1FFFF), s1 = (int)(sorted2[e + 1] & 0x1FFFF);
        float4 v0 = xp[s0 * 2], w0 = xp[s0 * 2 + 1];
        float4 v1 = xp[s1 * 2], w1 = xp[s1 * 2 + 1];
        a0 += v0.x; a1 += v0.y; a2 += v0.z; a3 += v0.w; a4 += w0.x;
        a0 += v1.x; a1 += v1.y; a2 += v1.z; a3 += v1.w; a4 += w1.x;
    }
    if (e < e1) {
        int s0 = (int)(sorted2[e] & 0x1FFFF);
        float4 v0 = xp[s0 * 2], w0 = xp[s0 * 2 + 1];
        a0 += v0.x; a1 += v0.y; a2 += v0.z; a3 += v0.w; a4 += w0.x;
    }
    float* o = agg + (long long)n * 5;
    o[0] = a0; o[1] = a1; o[2] = a2; o[3] = a3; o[4] = a4;
}

// ---------------- aggregation F=16 (layer 2): CSR, zero atomics -------------
// 2 lanes per node, each owns 8 features (two float4 gathers per edge)
__global__ __launch_bounds__(256) void agg16_csr(
    const unsigned int* __restrict__ sorted2, const int* __restrict__ row_ptr,
    const float4* __restrict__ h, float* __restrict__ agg, int N) {
    int t = blockIdx.x * 256 + threadIdx.x;
    int n = t >> 1, q = t & 1;
    if (n >= N) return;
    int e0 = row_ptr[n], e1 = row_ptr[n + 1];
    float a0 = 0, a1 = 0, a2 = 0, a3 = 0, a4 = 0, a5 = 0, a6 = 0, a7 = 0;
    int e = e0;
    for (; e + 1 < e1; e += 2) {
        int s0 = (int)(sorted2[e] & 0x1FFFF), s1 = (int)(sorted2[e + 1] & 0x1FFFF);
        float4 v0 = h[s0 * 4 + q * 2],     u0 = h[s0 * 4 + q * 2 + 1];
        float4 v1 = h[s1 * 4 + q * 2],     u1 = h[s1 * 4 + q * 2 + 1];
        a0 += v0.x; a1 += v0.y; a2 += v0.z; a3 += v0.w;
        a4 += u0.x; a5 += u0.y; a6 += u0.z; a7 += u0.w;
        a0 += v1.x; a1 += v1.y; a2 += v1.z; a3 += v1.w;
        a4 += u1.x; a5 += u1.y; a6 += u1.z; a7 += u1.w;
    }
    if (e < e1) {
        int s0 = (int)(sorted2[e] & 0x1FFFF);
        float4 v0 = h[s0 * 4 + q * 2], u0 = h[s0 * 4 + q * 2 + 1];
        a0 += v0.x; a1 += v0.y; a2 += v0.z; a3 += v0.w;
        a4 += u0.x; a5 += u0.y; a6 += u0.z; a7 += u0.w;
    }
    float4* o = (float4*)(agg + (long long)n * 16 + q * 8);
    o[0] = make_float4(a0, a1, a2, a3);
    o[1] = make_float4(a4, a5, a6, a7);
}

// ------------- MLP1: h = relu((x+agg1)@W1a+b1a)@W1b+b1b  (fp32 h) -----------
__global__ void mlp1_kernel(const float* __restrict__ x,
                            const float* __restrict__ agg,
                            const float* __restrict__ W1, const float* __restrict__ b1,
                            const float* __restrict__ W2, const float* __restrict__ b2,
                            float* __restrict__ h, int N) {
    int n = blockIdx.x * blockDim.x + threadIdx.x;
    if (n >= N) return;
    float in[5];
#pragma unroll
    for (int f = 0; f < 5; ++f)
        in[f] = x[(long long)n * 5 + f] + agg[(long long)n * 5 + f];
    float hid[16];
#pragma unroll
    for (int j = 0; j < 16; ++j) {
        float acc = b1[j];
#pragma unroll
        for (int f = 0; f < 5; ++f) acc = fmaf(in[f], W1[f * 16 + j], acc);
        hid[j] = fmaxf(acc, 0.0f);
    }
    float4* op = (float4*)(h + (long long)n * 16);
#pragma unroll
    for (int jq = 0; jq < 4; ++jq) {
        float4 v;
        float acc;
        acc = b2[jq * 4 + 0];
#pragma unroll
        for (int k = 0; k < 16; ++k) acc = fmaf(hid[k], W2[k * 16 + jq * 4 + 0], acc);
        v.x = acc;
        acc = b2[jq * 4 + 1];
#pragma unroll
        for (int k = 0; k < 16; ++k) acc = fmaf(hid[k], W2[k * 16 + jq * 4 + 1], acc);
        v.y = acc;
        acc = b2[jq * 4 + 2];
#pragma unroll
        for (int k = 0; k < 16; ++k) acc = fmaf(hid[k], W2[k * 16 + jq * 4 + 2], acc);
        v.z = acc;
        acc = b2[jq * 4 + 3];
#pragma unroll
        for (int k = 0; k < 16; ++k) acc = fmaf(hid[k], W2[k * 16 + jq * 4 + 3], acc);
        v.w = acc;
        op[jq] = v;
    }
}

// ------------- MLP2: out = relu((h+agg2)@W2a+b2a)@W2b+b2b -------------------
__global__ void mlp2_kernel(const float* __restrict__ h,
                            const float* __restrict__ agg,
                            const float* __restrict__ W1, const float* __restrict__ b1,
                            const float* __restrict__ W2, const float* __restrict__ b2,
                            float* __restrict__ out, int N) {
    int n = blockIdx.x * blockDim.x + threadIdx.x;
    if (n >= N) return;
    float in[16];
    const float4* hp = (const float4*)(h + (long long)n * 16);
    const float4* ap = (const float4*)(agg + (long long)n * 16);
#pragma unroll
    for (int qq = 0; qq < 4; ++qq) {
        float4 a = hp[qq], b = ap[qq];
        in[qq * 4 + 0] = a.x + b.x; in[qq * 4 + 1] = a.y + b.y;
        in[qq * 4 + 2] = a.z + b.z; in[qq * 4 + 3] = a.w + b.w;
    }
    float hid[16];
#pragma unroll
    for (int j = 0; j < 16; ++j) {
        float acc = b1[j];
#pragma unroll
        for (int f = 0; f < 16; ++f) acc = fmaf(in[f], W1[f * 16 + j], acc);
        hid[j] = fmaxf(acc, 0.0f);
    }
    float4* op = (float4*)(out + (long long)n * 16);
#pragma unroll
    for (int jq = 0; jq < 4; ++jq) {
        float4 v;
        float acc;
        acc = b2[jq * 4 + 0];
#pragma unroll
        for (int k = 0; k < 16; ++k) acc = fmaf(hid[k], W2[k * 16 + jq * 4 + 0], acc);
        v.x = acc;
        acc = b2[jq * 4 + 1];
#pragma unroll
        for (int k = 0; k < 16; ++k) acc = fmaf(hid[k], W2[k * 16 + jq * 4 + 1], acc);
        v.y = acc;
        acc = b2[jq * 4 + 2];
#pragma unroll
        for (int k = 0; k < 16; ++k) acc = fmaf(hid[k], W2[k * 16 + jq * 4 + 2], acc);
        v.z = acc;
        acc = b2[jq * 4 + 3];
#pragma unroll
        for (int k = 0; k < 16; ++k) acc = fmaf(hid[k], W2[k * 16 + jq * 4 + 3], acc);
        v.w = acc;
        op[jq] = v;
    }
}

// ---------- fallback path (ws too small): global atomics, fp32 --------------
__device__ __forceinline__ void load_edge(const void* eidx, unsigned int is32,
                                          int i, int E, int& s, int& d) {
    if (is32 == 0u) {
        const long long* p = (const long long*)eidx;
        s = (int)p[i]; d = (int)p[E + i];
    } else {
        const int* p = (const int*)eidx;
        s = p[i]; d = p[E + i];
    }
}

__global__ void scatter_f5_kernel(const void* __restrict__ eidx,
                                  const unsigned int* __restrict__ flag,
                                  const float* __restrict__ x,
                                  float* __restrict__ agg, int E) {
    int i = blockIdx.x * blockDim.x + threadIdx.x;
    if (i >= E) return;
    int s, d; load_edge(eidx, *flag, i, E, s, d);
    const float* xs = x + (long long)s * 5;
    float* a = agg + (long long)d * 5;
#pragma unroll
    for (int f = 0; f < 5; ++f) atomicAdd(&a[f], xs[f]);
}

__global__ void scatter_f16_kernel(const void* __restrict__ eidx,
                                   const unsigned int* __restrict__ flag,
                                   const float* __restrict__ h,
                                   float* __restrict__ agg, int E) {
    int i = blockIdx.x * blockDim.x + threadIdx.x;
    if (i >= E) return;
    int s, d; load_edge(eidx, *flag, i, E, s, d);
    const float* hs = h + (long long)s * 16;
    float* a = agg + (long long)d * 16;
#pragma unroll
    for (int f = 0; f < 16; ++f) atomicAdd(&a[f], hs[f]);
}

extern "C" void kernel_launch(void* const* d_in, const int* in_sizes, int n_in,
                              void* d_out, int out_size, void* d_ws, size_t ws_size,
                              hipStream_t stream) {
    const float* x    = (const float*)d_in[0];
    const void*  eidx = d_in[1];
    const float* W1a  = (const float*)d_in[2];
    const float* b1a  = (const float*)d_in[3];
    const float* W1b  = (const float*)d_in[4];
    const float* b1b  = (const float*)d_in[5];
    const float* W2a  = (const float*)d_in[6];
    const float* b2a  = (const float*)d_in[7];
    const float* W2b  = (const float*)d_in[8];
    const float* b2b  = (const float*)d_in[9];
    float* out = (float*)d_out;

    const int E = in_sizes[1] / 2;
    const int N = N_NODES;

    char* ws = (char*)d_ws;
    auto align256 = [](size_t v) { return (v + 255) & ~(size_t)255; };
    const size_t hist_bytes = (size_t)NCHUNK * NBIN_D * 4;             // 200,704

    const size_t off_flag     = 0;
    const size_t off_binstart = 256;                                    // 99*4
    const size_t off_totals   = 1024;                                   // 98*4
    const size_t off_rowptr   = 4096;                                   // 100001*4
    const size_t off_hist     = align256(off_rowptr + ((size_t)N + 1) * 4);
    const size_t off_offrel   = align256(off_hist + hist_bytes);
    const size_t off_xp       = align256(off_offrel + hist_bytes);      // N*32 fp32x8
    const size_t off_sorted1  = align256(off_xp + (size_t)N * 32);      // E*4
    const size_t off_sorted2  = align256(off_sorted1 + (size_t)E * 4);  // E*4
    const size_t need         = off_sorted2 + (size_t)E * 4;

    // agg1/agg2/h alias the dead sorted1 region after dlsort:
    //   agg1 @ +0        (N*5*4  = 2.0 MB)
    //   agg2 @ +2 MiB    (N*16*4 = 6.4 MB)
    //   h    @ +9 MiB    (N*16*4 = 6.4 MB)   total 15.8 MB < E*4 = 25.6 MB
    unsigned int* flag = (unsigned int*)(ws + off_flag);

    if (ws_size >= need && (size_t)E * 4 >= 9 * 1024 * 1024 + (size_t)N * 64) {
        int* bin_start        = (int*)(ws + off_binstart);
        int* totals           = (int*)(ws + off_totals);
        int* row_ptr          = (int*)(ws + off_rowptr);
        int* hist             = (int*)(ws + off_hist);
        int* off_rel          = (int*)(ws + off_offrel);
        float4* xp            = (float4*)(ws + off_xp);
        unsigned int* sorted1 = (unsigned int*)(ws + off_sorted1);
        unsigned int* sorted2 = (unsigned int*)(ws + off_sorted2);
        float* agg1 = (float*)(ws + off_sorted1);
        float* agg2 = (float*)(ws + off_sorted1 + 2 * 1024 * 1024);
        float* h    = (float*)(ws + off_sorted1 + 9 * 1024 * 1024);

        hipMemsetAsync(ws, 0, 4, stream);
        detect_i64_kernel<<<8, 256, 0, stream>>>((const unsigned int*)eidx, flag);
        pad_x_kernel<<<(N + 255) / 256, 256, 0, stream>>>(x, xp, N);
        count_kernel<<<NCHUNK, 256, 0, stream>>>(eidx, flag, hist, E);
        scan1_kernel<<<(NBIN_D * 64 + 511) / 512, 512, 0, stream>>>(hist, off_rel, totals);
        scan2_kernel<<<1, 1024, 0, stream>>>(totals, bin_start);
        scatter1_kernel<<<NCHUNK, 256, 0, stream>>>(eidx, flag, off_rel, bin_start, sorted1, E);
        dlsort_kernel<<<NBIN_D, 1024, 0, stream>>>(sorted1, bin_start, sorted2, row_ptr, N);

        agg5_csr<<<(N + 255) / 256, 256, 0, stream>>>(sorted2, row_ptr, xp, agg1, N);
        mlp1_kernel<<<(N + 255) / 256, 256, 0, stream>>>(x, agg1, W1a, b1a, W1b, b1b, h, N);
        agg16_csr<<<(2 * N + 255) / 256, 256, 0, stream>>>(sorted2, row_ptr, (const float4*)h, agg2, N);
        mlp2_kernel<<<(N + 255) / 256, 256, 0, stream>>>(h, agg2, W2a, b2a, W2b, b2b, out, N);
    } else {
        // fallback: global-atomic path
        const size_t f_agg1 = 4096;
        const size_t f_agg2 = f_agg1 + 2 * 1024 * 1024;
        const size_t f_h    = f_agg2 + 7 * 1024 * 1024;
        float* agg1 = (float*)(ws + f_agg1);
        float* agg2 = (float*)(ws + f_agg2);
        float* h    = (float*)(ws + f_h);

        hipMemsetAsync(ws, 0, f_agg2 + (size_t)N * 16 * 4, stream);
        detect_i64_kernel<<<8, 256, 0, stream>>>((const unsigned int*)eidx, flag);
        int blocks = (E + 255) / 256;
        scatter_f5_kernel<<<blocks, 256, 0, stream>>>(eidx, flag, x, agg1, E);
        mlp1_kernel<<<(N + 255) / 256, 256, 0, stream>>>(x, agg1, W1a, b1a, W1b, b1b, h, N);
        scatter_f16_kernel<<<blocks, 256, 0, stream>>>(eidx, flag, h, agg2, E);
        mlp2_kernel<<<(N + 255) / 256, 256, 0, stream>>>(h, agg2, W2a, b2a, W2b, b2b, out, N);
    }
}

// Round 7
// 279.556 us; speedup vs baseline: 3.1479x; 1.3368x over previous
//
#include <hip/hip_runtime.h>

#define N_NODES 100000
#define NBIN_D  98            // dst bins of 1024 nodes
#define NW      4             // src windows: src>>15 (100000 < 4*32768)
#define NBINS_TOT (NW * NBIN_D)   // 392 sort bins, w-major
#define NCHUNK  512

// ---------------- dtype detection (int64 vs int32 edge_index) ---------------
// edge values < 2^31. If int64 LE, every odd 32-bit word is 0.
__global__ void detect_i64_kernel(const unsigned int* __restrict__ e,
                                  unsigned int* __restrict__ flag) {
    int i = blockIdx.x * blockDim.x + threadIdx.x;  // 0..2047
    unsigned int v = e[2 * i + 1];
    if (v != 0u) atomicOr(flag, 1u);
}

// ---------------- pad x (N x 5 f32) -> fp32x8 (32B rows) --------------------
__global__ void pad_x_kernel(const float* __restrict__ x, float4* __restrict__ xp, int N) {
    int n = blockIdx.x * blockDim.x + threadIdx.x;
    if (n >= N) return;
    const float* p = x + (long long)n * 5;
    xp[n * 2]     = make_float4(p[0], p[1], p[2], p[3]);
    xp[n * 2 + 1] = make_float4(p[4], 0.f, 0.f, 0.f);
}

// ---------------- pass 1a: per-chunk histogram over (w, dst_bin) ------------
__global__ void count_kernel(const void* __restrict__ eidx,
                             const unsigned int* __restrict__ flag,
                             int* __restrict__ hist, int E) {
    __shared__ int lh[NBINS_TOT];
    int tid = threadIdx.x, c = blockIdx.x;
    for (int i = tid; i < NBINS_TOT; i += blockDim.x) lh[i] = 0;
    __syncthreads();
    int per = (E + NCHUNK - 1) / NCHUNK;
    int e0 = c * per, e1 = min(E, e0 + per);
    unsigned int is32 = *flag;
    for (int e = e0 + tid; e < e1; e += blockDim.x) {
        int s, d;
        if (is32) {
            const int* p = (const int*)eidx; s = p[e]; d = p[E + e];
        } else {
            const long long* p = (const long long*)eidx; s = (int)p[e]; d = (int)p[E + e];
        }
        atomicAdd(&lh[(s >> 15) * NBIN_D + (d >> 10)], 1);
    }
    __syncthreads();
    for (int i = tid; i < NBINS_TOT; i += blockDim.x) hist[c * NBINS_TOT + i] = lh[i];
}

// ---------------- pass 1b: per-bin column scan (1 wave per bin) -------------
__global__ void scan1_kernel(const int* __restrict__ hist,
                             int* __restrict__ off_rel,
                             int* __restrict__ totals) {
    int gtid = blockIdx.x * blockDim.x + threadIdx.x;
    int b = gtid >> 6;
    int lane = threadIdx.x & 63;
    if (b >= NBINS_TOT) return;
    int carry = 0;
    for (int k = 0; k < NCHUNK; k += 64) {
        int v = hist[(k + lane) * NBINS_TOT + b];
        int sc = v;
        for (int off = 1; off < 64; off <<= 1) {
            int t = __shfl_up(sc, off);
            if (lane >= off) sc += t;
        }
        off_rel[(k + lane) * NBINS_TOT + b] = carry + sc - v;   // exclusive
        carry += __shfl(sc, 63);
    }
    if (lane == 0) totals[b] = carry;
}

// ---------------- pass 1c: scan bin totals -> bin_start ---------------------
__global__ void scan2_kernel(const int* __restrict__ totals,
                             int* __restrict__ bin_start) {
    __shared__ int buf[1024];
    int tid = threadIdx.x;
    buf[tid] = (tid < NBINS_TOT) ? totals[tid] : 0;
    __syncthreads();
    for (int off = 1; off < 1024; off <<= 1) {
        int v = (tid >= off) ? buf[tid - off] : 0;
        __syncthreads();
        buf[tid] += v;
        __syncthreads();
    }
    if (tid < NBINS_TOT) bin_start[tid + 1] = buf[tid];
    if (tid == 0) bin_start[0] = 0;
}

// ---------------- pass 1d: scatter edges into (w, dst_bin) order ------------
// packed edge word: (dl << 17) | src   (dl = dst & 1023, src < 2^17)
__global__ void scatter1_kernel(const void* __restrict__ eidx,
                                const unsigned int* __restrict__ flag,
                                const int* __restrict__ off_rel,
                                const int* __restrict__ bin_start,
                                unsigned int* __restrict__ sorted1, int E) {
    __shared__ int lcnt[NBINS_TOT];
    __shared__ int lbase[NBINS_TOT];
    int tid = threadIdx.x, c = blockIdx.x;
    for (int i = tid; i < NBINS_TOT; i += blockDim.x) {
        lcnt[i] = 0;
        lbase[i] = bin_start[i] + off_rel[c * NBINS_TOT + i];
    }
    __syncthreads();
    int per = (E + NCHUNK - 1) / NCHUNK;
    int e0 = c * per, e1 = min(E, e0 + per);
    unsigned int is32 = *flag;
    for (int e = e0 + tid; e < e1; e += blockDim.x) {
        int s, d;
        if (is32) {
            const int* p = (const int*)eidx; s = p[e]; d = p[E + e];
        } else {
            const long long* p = (const long long*)eidx; s = (int)p[e]; d = (int)p[E + e];
        }
        int b = (s >> 15) * NBIN_D + (d >> 10);
        int dl = d & 1023;
        int pos = lbase[b] + atomicAdd(&lcnt[b], 1);
        sorted1[pos] = ((unsigned int)dl << 17) | (unsigned int)s;
    }
}

// ---------------- pass 2: per-(w,bin) counting sort by dl -> window CSR -----
// rp[w*(N+1) + n] .. rp[w*(N+1) + n + 1] = node n's edges in window w
__global__ __launch_bounds__(1024) void dlsort_kernel(
    const unsigned int* __restrict__ sorted1,
    const int* __restrict__ bin_start,
    unsigned int* __restrict__ sorted2,
    int* __restrict__ rp, int N) {
    __shared__ int hist[1024];
    __shared__ int scanv[1024];
    __shared__ int offc[1024];
    int tid = threadIdx.x, b = blockIdx.x;
    int w = b / NBIN_D, dbin = b - w * NBIN_D;
    int bs = bin_start[b], be = bin_start[b + 1];
    hist[tid] = 0;
    __syncthreads();
    for (int e = bs + tid; e < be; e += 1024)
        atomicAdd(&hist[sorted1[e] >> 17], 1);
    __syncthreads();
    scanv[tid] = hist[tid];
    __syncthreads();
    for (int off = 1; off < 1024; off <<= 1) {
        int v = (tid >= off) ? scanv[tid - off] : 0;
        __syncthreads();
        scanv[tid] += v;
        __syncthreads();
    }
    int excl = scanv[tid] - hist[tid];
    offc[tid] = excl;
    int node = dbin * 1024 + tid;
    if (node < N) rp[w * (N + 1) + node] = bs + excl;
    if (node == N) rp[w * (N + 1) + N] = be;   // dbin=97, tid=672
    __syncthreads();
    for (int e = bs + tid; e < be; e += 1024) {
        unsigned int ww = sorted1[e];
        int pos = bs + atomicAdd(&offc[ww >> 17], 1);
        sorted2[pos] = ww;
    }
}

// ---------------- aggregation F=5 (layer 1): window CSR, zero atomics -------
__global__ __launch_bounds__(256) void agg5_csr(
    const unsigned int* __restrict__ sorted2, const int* __restrict__ rp,
    const float4* __restrict__ xp, float* __restrict__ agg, int N) {
    int n = blockIdx.x * 256 + threadIdx.x;
    if (n >= N) return;
    float a0 = 0, a1 = 0, a2 = 0, a3 = 0, a4 = 0;
#pragma unroll
    for (int w = 0; w < NW; ++w) {
        int e0 = rp[w * (N + 1) + n], e1 = rp[w * (N + 1) + n + 1];
        int e = e0;
        for (; e + 1 < e1; e += 2) {
            int s0 = (int)(sorted2[e] & 0x1FFFF), s1 = (int)(sorted2[e + 1] & 0x1FFFF);
            float4 v0 = xp[s0 * 2], w0 = xp[s0 * 2 + 1];
            float4 v1 = xp[s1 * 2], w1 = xp[s1 * 2 + 1];
            a0 += v0.x; a1 += v0.y; a2 += v0.z; a3 += v0.w; a4 += w0.x;
            a0 += v1.x; a1 += v1.y; a2 += v1.z; a3 += v1.w; a4 += w1.x;
        }
        if (e < e1) {
            int s0 = (int)(sorted2[e] & 0x1FFFF);
            float4 v0 = xp[s0 * 2], w0 = xp[s0 * 2 + 1];
            a0 += v0.x; a1 += v0.y; a2 += v0.z; a3 += v0.w; a4 += w0.x;
        }
    }
    float* o = agg + (long long)n * 5;
    o[0] = a0; o[1] = a1; o[2] = a2; o[3] = a3; o[4] = a4;
}

// ---------------- aggregation F=16 (layer 2): window CSR, zero atomics ------
// 2 lanes per node, each owns 8 features (two float4 gathers per edge)
__global__ __launch_bounds__(256) void agg16_csr(
    const unsigned int* __restrict__ sorted2, const int* __restrict__ rp,
    const float4* __restrict__ h, float* __restrict__ agg, int N) {
    int t = blockIdx.x * 256 + threadIdx.x;
    int n = t >> 1, q = t & 1;
    if (n >= N) return;
    float a0 = 0, a1 = 0, a2 = 0, a3 = 0, a4 = 0, a5 = 0, a6 = 0, a7 = 0;
#pragma unroll
    for (int w = 0; w < NW; ++w) {
        int e0 = rp[w * (N + 1) + n], e1 = rp[w * (N + 1) + n + 1];
        int e = e0;
        for (; e + 1 < e1; e += 2) {
            int s0 = (int)(sorted2[e] & 0x1FFFF), s1 = (int)(sorted2[e + 1] & 0x1FFFF);
            float4 v0 = h[s0 * 4 + q * 2], u0 = h[s0 * 4 + q * 2 + 1];
            float4 v1 = h[s1 * 4 + q * 2], u1 = h[s1 * 4 + q * 2 + 1];
            a0 += v0.x; a1 += v0.y; a2 += v0.z; a3 += v0.w;
            a4 += u0.x; a5 += u0.y; a6 += u0.z; a7 += u0.w;
            a0 += v1.x; a1 += v1.y; a2 += v1.z; a3 += v1.w;
            a4 += u1.x; a5 += u1.y; a6 += u1.z; a7 += u1.w;
        }
        if (e < e1) {
            int s0 = (int)(sorted2[e] & 0x1FFFF);
            float4 v0 = h[s0 * 4 + q * 2], u0 = h[s0 * 4 + q * 2 + 1];
            a0 += v0.x; a1 += v0.y; a2 += v0.z; a3 += v0.w;
            a4 += u0.x; a5 += u0.y; a6 += u0.z; a7 += u0.w;
        }
    }
    float4* o = (float4*)(agg + (long long)n * 16 + q * 8);
    o[0] = make_float4(a0, a1, a2, a3);
    o[1] = make_float4(a4, a5, a6, a7);
}

// ------------- MLP1: h = relu((x+agg1)@W1a+b1a)@W1b+b1b  (fp32 h) -----------
__global__ void mlp1_kernel(const float* __restrict__ x,
                            const float* __restrict__ agg,
                            const float* __restrict__ W1, const float* __restrict__ b1,
                            const float* __restrict__ W2, const float* __restrict__ b2,
                            float* __restrict__ h, int N) {
    int n = blockIdx.x * blockDim.x + threadIdx.x;
    if (n >= N) return;
    float in[5];
#pragma unroll
    for (int f = 0; f < 5; ++f)
        in[f] = x[(long long)n * 5 + f] + agg[(long long)n * 5 + f];
    float hid[16];
#pragma unroll
    for (int j = 0; j < 16; ++j) {
        float acc = b1[j];
#pragma unroll
        for (int f = 0; f < 5; ++f) acc = fmaf(in[f], W1[f * 16 + j], acc);
        hid[j] = fmaxf(acc, 0.0f);
    }
    float4* op = (float4*)(h + (long long)n * 16);
#pragma unroll
    for (int jq = 0; jq < 4; ++jq) {
        float4 v;
        float acc;
        acc = b2[jq * 4 + 0];
#pragma unroll
        for (int k = 0; k < 16; ++k) acc = fmaf(hid[k], W2[k * 16 + jq * 4 + 0], acc);
        v.x = acc;
        acc = b2[jq * 4 + 1];
#pragma unroll
        for (int k = 0; k < 16; ++k) acc = fmaf(hid[k], W2[k * 16 + jq * 4 + 1], acc);
        v.y = acc;
        acc = b2[jq * 4 + 2];
#pragma unroll
        for (int k = 0; k < 16; ++k) acc = fmaf(hid[k], W2[k * 16 + jq * 4 + 2], acc);
        v.z = acc;
        acc = b2[jq * 4 + 3];
#pragma unroll
        for (int k = 0; k < 16; ++k) acc = fmaf(hid[k], W2[k * 16 + jq * 4 + 3], acc);
        v.w = acc;
        op[jq] = v;
    }
}

// ------------- MLP2: out = relu((h+agg2)@W2a+b2a)@W2b+b2b -------------------
__global__ void mlp2_kernel(const float* __restrict__ h,
                            const float* __restrict__ agg,
                            const float* __restrict__ W1, const float* __restrict__ b1,
                            const float* __restrict__ W2, const float* __restrict__ b2,
                            float* __restrict__ out, int N) {
    int n = blockIdx.x * blockDim.x + threadIdx.x;
    if (n >= N) return;
    float in[16];
    const float4* hp = (const float4*)(h + (long long)n * 16);
    const float4* ap = (const float4*)(agg + (long long)n * 16);
#pragma unroll
    for (int qq = 0; qq < 4; ++qq) {
        float4 a = hp[qq], b = ap[qq];
        in[qq * 4 + 0] = a.x + b.x; in[qq * 4 + 1] = a.y + b.y;
        in[qq * 4 + 2] = a.z + b.z; in[qq * 4 + 3] = a.w + b.w;
    }
    float hid[16];
#pragma unroll
    for (int j = 0; j < 16; ++j) {
        float acc = b1[j];
#pragma unroll
        for (int f = 0; f < 16; ++f) acc = fmaf(in[f], W1[f * 16 + j], acc);
        hid[j] = fmaxf(acc, 0.0f);
    }
    float4* op = (float4*)(out + (long long)n * 16);
#pragma unroll
    for (int jq = 0; jq < 4; ++jq) {
        float4 v;
        float acc;
        acc = b2[jq * 4 + 0];
#pragma unroll
        for (int k = 0; k < 16; ++k) acc = fmaf(hid[k], W2[k * 16 + jq * 4 + 0], acc);
        v.x = acc;
        acc = b2[jq * 4 + 1];
#pragma unroll
        for (int k = 0; k < 16; ++k) acc = fmaf(hid[k], W2[k * 16 + jq * 4 + 1], acc);
        v.y = acc;
        acc = b2[jq * 4 + 2];
#pragma unroll
        for (int k = 0; k < 16; ++k) acc = fmaf(hid[k], W2[k * 16 + jq * 4 + 2], acc);
        v.z = acc;
        acc = b2[jq * 4 + 3];
#pragma unroll
        for (int k = 0; k < 16; ++k) acc = fmaf(hid[k], W2[k * 16 + jq * 4 + 3], acc);
        v.w = acc;
        op[jq] = v;
    }
}

// ---------- fallback path (ws too small): global atomics, fp32 --------------
__device__ __forceinline__ void load_edge(const void* eidx, unsigned int is32,
                                          int i, int E, int& s, int& d) {
    if (is32 == 0u) {
        const long long* p = (const long long*)eidx;
        s = (int)p[i]; d = (int)p[E + i];
    } else {
        const int* p = (const int*)eidx;
        s = p[i]; d = p[E + i];
    }
}

__global__ void scatter_f5_kernel(const void* __restrict__ eidx,
                                  const unsigned int* __restrict__ flag,
                                  const float* __restrict__ x,
                                  float* __restrict__ agg, int E) {
    int i = blockIdx.x * blockDim.x + threadIdx.x;
    if (i >= E) return;
    int s, d; load_edge(eidx, *flag, i, E, s, d);
    const float* xs = x + (long long)s * 5;
    float* a = agg + (long long)d * 5;
#pragma unroll
    for (int f = 0; f < 5; ++f) atomicAdd(&a[f], xs[f]);
}

__global__ void scatter_f16_kernel(const void* __restrict__ eidx,
                                   const unsigned int* __restrict__ flag,
                                   const float* __restrict__ h,
                                   float* __restrict__ agg, int E) {
    int i = blockIdx.x * blockDim.x + threadIdx.x;
    if (i >= E) return;
    int s, d; load_edge(eidx, *flag, i, E, s, d);
    const float* hs = h + (long long)s * 16;
    float* a = agg + (long long)d * 16;
#pragma unroll
    for (int f = 0; f < 16; ++f) atomicAdd(&a[f], hs[f]);
}

extern "C" void kernel_launch(void* const* d_in, const int* in_sizes, int n_in,
                              void* d_out, int out_size, void* d_ws, size_t ws_size,
                              hipStream_t stream) {
    const float* x    = (const float*)d_in[0];
    const void*  eidx = d_in[1];
    const float* W1a  = (const float*)d_in[2];
    const float* b1a  = (const float*)d_in[3];
    const float* W1b  = (const float*)d_in[4];
    const float* b1b  = (const float*)d_in[5];
    const float* W2a  = (const float*)d_in[6];
    const float* b2a  = (const float*)d_in[7];
    const float* W2b  = (const float*)d_in[8];
    const float* b2b  = (const float*)d_in[9];
    float* out = (float*)d_out;

    const int E = in_sizes[1] / 2;
    const int N = N_NODES;

    char* ws = (char*)d_ws;
    auto align256 = [](size_t v) { return (v + 255) & ~(size_t)255; };
    const size_t hist_bytes = (size_t)NCHUNK * NBINS_TOT * 4;          // 802,816

    const size_t off_flag     = 0;
    const size_t off_binstart = 256;                                    // 393*4
    const size_t off_totals   = align256(off_binstart + (NBINS_TOT + 1) * 4);
    const size_t off_rp       = align256(off_totals + NBINS_TOT * 4);   // NW*(N+1)*4
    const size_t off_hist     = align256(off_rp + (size_t)NW * (N + 1) * 4);
    const size_t off_offrel   = align256(off_hist + hist_bytes);
    const size_t off_xp       = align256(off_offrel + hist_bytes);      // N*32 fp32x8
    const size_t off_sorted1  = align256(off_xp + (size_t)N * 32);      // E*4
    const size_t off_sorted2  = align256(off_sorted1 + (size_t)E * 4);  // E*4
    const size_t need         = off_sorted2 + (size_t)E * 4;

    // agg1/agg2/h alias the dead sorted1 region after dlsort:
    //   agg1 @ +0        (N*5*4  = 2.0 MB)
    //   agg2 @ +2 MiB    (N*16*4 = 6.4 MB)
    //   h    @ +9 MiB    (N*16*4 = 6.4 MB)   total 15.8 MB < E*4 = 25.6 MB
    unsigned int* flag = (unsigned int*)(ws + off_flag);

    if (ws_size >= need && (size_t)E * 4 >= 9 * 1024 * 1024 + (size_t)N * 64) {
        int* bin_start        = (int*)(ws + off_binstart);
        int* totals           = (int*)(ws + off_totals);
        int* rp               = (int*)(ws + off_rp);
        int* hist             = (int*)(ws + off_hist);
        int* off_rel          = (int*)(ws + off_offrel);
        float4* xp            = (float4*)(ws + off_xp);
        unsigned int* sorted1 = (unsigned int*)(ws + off_sorted1);
        unsigned int* sorted2 = (unsigned int*)(ws + off_sorted2);
        float* agg1 = (float*)(ws + off_sorted1);
        float* agg2 = (float*)(ws + off_sorted1 + 2 * 1024 * 1024);
        float* h    = (float*)(ws + off_sorted1 + 9 * 1024 * 1024);

        hipMemsetAsync(ws, 0, 4, stream);
        detect_i64_kernel<<<8, 256, 0, stream>>>((const unsigned int*)eidx, flag);
        pad_x_kernel<<<(N + 255) / 256, 256, 0, stream>>>(x, xp, N);
        count_kernel<<<NCHUNK, 256, 0, stream>>>(eidx, flag, hist, E);
        scan1_kernel<<<(NBINS_TOT * 64 + 511) / 512, 512, 0, stream>>>(hist, off_rel, totals);
        scan2_kernel<<<1, 1024, 0, stream>>>(totals, bin_start);
        scatter1_kernel<<<NCHUNK, 256, 0, stream>>>(eidx, flag, off_rel, bin_start, sorted1, E);
        dlsort_kernel<<<NBINS_TOT, 1024, 0, stream>>>(sorted1, bin_start, sorted2, rp, N);

        agg5_csr<<<(N + 255) / 256, 256, 0, stream>>>(sorted2, rp, xp, agg1, N);
        mlp1_kernel<<<(N + 255) / 256, 256, 0, stream>>>(x, agg1, W1a, b1a, W1b, b1b, h, N);
        agg16_csr<<<(2 * N + 255) / 256, 256, 0, stream>>>(sorted2, rp, (const float4*)h, agg2, N);
        mlp2_kernel<<<(N + 255) / 256, 256, 0, stream>>>(h, agg2, W2a, b2a, W2b, b2b, out, N);
    } else {
        // fallback: global-atomic path
        const size_t f_agg1 = 4096;
        const size_t f_agg2 = f_agg1 + 2 * 1024 * 1024;
        const size_t f_h    = f_agg2 + 7 * 1024 * 1024;
        float* agg1 = (float*)(ws + f_agg1);
        float* agg2 = (float*)(ws + f_agg2);
        float* h    = (float*)(ws + f_h);

        hipMemsetAsync(ws, 0, f_agg2 + (size_t)N * 16 * 4, stream);
        detect_i64_kernel<<<8, 256, 0, stream>>>((const unsigned int*)eidx, flag);
        int blocks = (E + 255) / 256;
        scatter_f5_kernel<<<blocks, 256, 0, stream>>>(eidx, flag, x, agg1, E);
        mlp1_kernel<<<(N + 255) / 256, 256, 0, stream>>>(x, agg1, W1a, b1a, W1b, b1b, h, N);
        scatter_f16_kernel<<<blocks, 256, 0, stream>>>(eidx, flag, h, agg2, E);
        mlp2_kernel<<<(N + 255) / 256, 256, 0, stream>>>(h, agg2, W2a, b2a, W2b, b2b, out, N);
    }
}